// Round 6
// baseline (36.226 us; speedup 1.0000x reference)
//
#include <hip/hip_runtime.h>
#include <math.h>

#define NTOT 131072
#define NSIG 64
#define SEGL 2048
#define NIN 256

// ws layout (bytes):
//   [0, 524288)        y[131072] f32
//   [524288, 1048576)  w_all[64][2048] f32 (normalized; only [1024-D,1024+min(D,1023)] written)
//   [1048576, 1048832) Dv[64] int
// Truncation: taps beyond |d| = 12|sigma|+4 are exp(<-72) == 0 in f32 and
// Z >= 1 (peak tap exp(0)=1), so truncation error ~1e-28 absolute.

// ---------------------------------------------------------------------------
// K1: y = x@W3 + b3, each column ONCE, float2 per thread (no halo).
// 256 blocks x 256 threads x 2 cols = 131072: exactly one resident round
// (1 block/CU, 4 waves/CU), no round-2 skew behind the duty tail.
// Duty blocks (bx0 < 64) fold the MLP dot into the same unrolled stream loop
// (W1 rides under W3's HBM latency), then window for segment bx0.
// ---------------------------------------------------------------------------
__global__ __launch_bounds__(256) void k_y(
    const float* __restrict__ x,  const float* __restrict__ W1,
    const float* __restrict__ b1, const float* __restrict__ W2,
    const float* __restrict__ b2, const float* __restrict__ W3,
    const float* __restrict__ b3, float* __restrict__ y,
    float* __restrict__ w_all, int* __restrict__ Dv)
{
  __shared__ float xl[NIN];
  __shared__ float sl[256];
  __shared__ float red[4];
  __shared__ float bc[2];

  const int t = threadIdx.x;
  const int bx0 = (int)blockIdx.x;
  // bijective XCD swizzle: 32 consecutive 512-col chunks per XCD
  const int bx = ((bx0 & 7) << 5) | (bx0 >> 3);
  const int col = (bx << 9) + (t << 1);

  xl[t] = x[t];
  __syncthreads();

  const float* p = W3 + col;
  const float2 bv = *reinterpret_cast<const float2*>(b3 + col);
  float a0 = bv.x, a1 = bv.y;

  if (bx0 < NSIG) {
    // ---- duty block: float2 stream + MLP in one loop ----
    float am = b1[t];
    #pragma unroll 16
    for (int n = 0; n < NIN; ++n) {
      const float xv = xl[n];
      const float2 wv = *reinterpret_cast<const float2*>(p + (size_t)n * NTOT);
      a0 = fmaf(xv, wv.x, a0);
      a1 = fmaf(xv, wv.y, a1);
      am = fmaf(xv, W1[n * 256 + t], am);
    }
    *reinterpret_cast<float2*>(y + col) = make_float2(a0, a1);
    sl[t] = am / (1.0f + expf(-am));
    __syncthreads();

    const int seg = bx0;
    float v = sl[t] * W2[t * NSIG + seg];
    #pragma unroll
    for (int o = 32; o > 0; o >>= 1) v += __shfl_down(v, o, 64);
    const int lane = t & 63, wid = t >> 6;
    if (lane == 0) red[wid] = v;
    __syncthreads();
    if (t == 0) bc[0] = red[0] + red[1] + red[2] + red[3] + b2[seg];
    __syncthreads();
    const float sig = bc[0];

    const float inv2 = 1.0f / (2.0f * sig * sig);
    const float Df = 12.0f * fabsf(sig) + 4.0f;
    const int D = (Df >= 1024.0f) ? 1024 : (int)Df;
    const int dlo = -D;
    const int dhi = (D < 1023) ? D : 1023;
    const int cnt = dhi - dlo + 1;

    float zp = 0.0f;
    for (int i = t; i < cnt; i += 256) {
      const float d = (float)(dlo + i);
      const float e = expf(-d * d * inv2);
      w_all[seg * SEGL + 1024 + dlo + i] = e;
      zp += e;
    }
    v = zp;
    #pragma unroll
    for (int o = 32; o > 0; o >>= 1) v += __shfl_down(v, o, 64);
    if (lane == 0) red[wid] = v;
    __syncthreads();
    if (t == 0) bc[1] = red[0] + red[1] + red[2] + red[3];
    __syncthreads();
    const float iZ = 1.0f / bc[1];
    for (int i = t; i < cnt; i += 256)
      w_all[seg * SEGL + 1024 + dlo + i] *= iZ;
    if (t == 0) Dv[seg] = D;
  } else {
    // ---- pure float2 stream ----
    #pragma unroll 16
    for (int n = 0; n < NIN; ++n) {
      const float xv = xl[n];
      const float2 wv = *reinterpret_cast<const float2*>(p + (size_t)n * NTOT);
      a0 = fmaf(xv, wv.x, a0);
      a1 = fmaf(xv, wv.y, a1);
    }
    *reinterpret_cast<float2*>(y + col) = make_float2(a0, a1);
  }
}

// ---------------------------------------------------------------------------
// K2: truncated "same" conv. 512 blocks x 256 threads; block bx handles
// outputs [seg*2048 + M0, +256), seg = bx>>3, M0 = (bx&7)*256.
// Stages only the live y span; window read directly (block-uniform -> scalar).
// out[m] = sum_d w[1024+d] * seg[m-1-d], d in [-D, min(D,1023)]
// ---------------------------------------------------------------------------
__global__ __launch_bounds__(256) void k_conv(
    const float* __restrict__ y, const float* __restrict__ w_all,
    const int* __restrict__ Dv, float* __restrict__ out)
{
  __shared__ float S[2560];   // seg coord = sbase + idx

  const int t = threadIdx.x;
  const int bx0 = (int)blockIdx.x;
  const int bx = ((bx0 & 7) << 6) | (bx0 >> 3);   // matches k_y column owner
  const int seg = bx >> 3;
  const int M0 = (bx & 7) << 8;
  const int sbase = M0 - 1026;

  const int D = Dv[seg];
  const int dlo = -D;
  const int dhi = (D < 1023) ? D : 1023;

  // live span of S: [1025-dhi, 1281+D)
  const int ilo = 1025 - dhi;
  const int ihi = 1281 + D;
  for (int i = ilo + t; i < ihi; i += 256) {
    const int g = sbase + i;
    S[i] = (g >= 0 && g < SEGL) ? y[seg * SEGL + g] : 0.0f;
  }
  __syncthreads();

  const float* wrow = w_all + seg * SEGL + 1024;
  float a = 0.0f;
  for (int d = dlo; d <= dhi; ++d)
    a = fmaf(wrow[d], S[t + 1025 - d], a);   // wrow[d] block-uniform
  out[seg * SEGL + M0 + t] = a;
}

// ---------------------------------------------------------------------------
extern "C" void kernel_launch(void* const* d_in, const int* in_sizes, int n_in,
                              void* d_out, int out_size, void* d_ws, size_t ws_size,
                              hipStream_t stream) {
  const float* x  = (const float*)d_in[0];
  const float* W1 = (const float*)d_in[1];
  const float* b1 = (const float*)d_in[2];
  const float* W2 = (const float*)d_in[3];
  const float* b2 = (const float*)d_in[4];
  const float* W3 = (const float*)d_in[5];
  const float* b3 = (const float*)d_in[6];
  float* out = (float*)d_out;

  char* ws = (char*)d_ws;
  float* y     = (float*)(ws);
  float* w_all = (float*)(ws + 524288);
  int*   Dv    = (int*)  (ws + 1048576);

  hipLaunchKernelGGL(k_y, dim3(256), dim3(256), 0, stream,
                     x, W1, b1, W2, b2, W3, b3, y, w_all, Dv);
  hipLaunchKernelGGL(k_conv, dim3(512), dim3(256), 0, stream,
                     y, w_all, Dv, out);
}

// Round 7
// 32.878 us; speedup vs baseline: 1.1018x; 1.1018x over previous
//
#include <hip/hip_runtime.h>
#include <math.h>

#define NTOT 131072
#define NSIG 64
#define SEGL 2048
#define NIN 256

// ws layout (bytes):
//   [0, 524288)        y[131072] f32
//   [524288, 1048576)  w_all[64][2048] f32 (normalized; only [1024-D,1024+min(D,1023)] written)
//   [1048576, 1048832) Dv[64] int
// Truncation: taps beyond |d| = 12|sigma|+4 are exp(<-72) == 0 in f32 and
// Z >= 1 (peak tap exp(0)=1), so truncation error ~1e-28 absolute.

// ---------------------------------------------------------------------------
// K1: y = x@W3 + b3. 512 blocks x 256 threads (2 blocks/CU, 8 waves/CU, all
// co-resident). Block owns 256 columns; thread t = (g = t>>7, p = t&127)
// accumulates column pair (2p, 2p+1) over row half n in [g*128, g*128+128)
// with float2 loads (512B per wave-instruction). Partials combined via LDS.
// Each W3 element read exactly once. Duty blocks (bx0 < 64) additionally run
// the tiny MLP (L2-resident W1) -> sigma -> truncated window for segment bx0.
// ---------------------------------------------------------------------------
__global__ __launch_bounds__(256) void k_y(
    const float* __restrict__ x,  const float* __restrict__ W1,
    const float* __restrict__ b1, const float* __restrict__ W2,
    const float* __restrict__ b2, const float* __restrict__ W3,
    const float* __restrict__ b3, float* __restrict__ y,
    float* __restrict__ w_all, int* __restrict__ Dv)
{
  __shared__ float xl[NIN];
  __shared__ float2 part[256];
  __shared__ float sl[256];
  __shared__ float red[4];
  __shared__ float bc[2];

  const int t = threadIdx.x;
  const int bx0 = (int)blockIdx.x;
  // bijective XCD swizzle: 64 consecutive 256-col chunks per XCD
  const int bx = ((bx0 & 7) << 6) | (bx0 >> 3);
  const int colbase = bx << 8;
  const int g = t >> 7;          // row half
  const int p = t & 127;         // column pair
  const int c = colbase + (p << 1);

  xl[t] = x[t];
  __syncthreads();

  // ---- stream: 128 float2 rows ----
  const float* wp = W3 + (size_t)(g << 7) * NTOT + c;
  float a0 = 0.0f, a1 = 0.0f;
  #pragma unroll 16
  for (int k = 0; k < 128; ++k) {
    const float xv = xl[(g << 7) + k];
    const float2 wv = *reinterpret_cast<const float2*>(wp + (size_t)k * NTOT);
    a0 = fmaf(xv, wv.x, a0);
    a1 = fmaf(xv, wv.y, a1);
  }
  part[t] = make_float2(a0, a1);
  __syncthreads();

  if (t < 128) {
    const float2 q0 = part[t];
    const float2 q1 = part[t + 128];
    const float2 bv = *reinterpret_cast<const float2*>(b3 + colbase + (t << 1));
    *reinterpret_cast<float2*>(y + colbase + (t << 1)) =
        make_float2(q0.x + q1.x + bv.x, q0.y + q1.y + bv.y);
  }

  if (bx0 >= NSIG) return;

  // ---- duty: MLP (W1 L2-resident after first touch) ----
  float am = b1[t];
  #pragma unroll 32
  for (int n = 0; n < NIN; ++n) am = fmaf(xl[n], W1[n * 256 + t], am);
  sl[t] = am / (1.0f + expf(-am));
  __syncthreads();

  // ---- sigma = s @ W2[:,seg] + b2[seg] ----
  const int seg = bx0;
  float v = sl[t] * W2[t * NSIG + seg];
  #pragma unroll
  for (int o = 32; o > 0; o >>= 1) v += __shfl_down(v, o, 64);
  const int lane = t & 63, wid = t >> 6;
  if (lane == 0) red[wid] = v;
  __syncthreads();
  if (t == 0) bc[0] = red[0] + red[1] + red[2] + red[3] + b2[seg];
  __syncthreads();
  const float sig = bc[0];

  // ---- truncated gaussian window ----
  const float inv2 = 1.0f / (2.0f * sig * sig);
  const float Df = 12.0f * fabsf(sig) + 4.0f;
  const int D = (Df >= 1024.0f) ? 1024 : (int)Df;
  const int dlo = -D;
  const int dhi = (D < 1023) ? D : 1023;
  const int cnt = dhi - dlo + 1;

  float zp = 0.0f;
  for (int i = t; i < cnt; i += 256) {
    const float d = (float)(dlo + i);
    const float e = expf(-d * d * inv2);
    w_all[seg * SEGL + 1024 + dlo + i] = e;
    zp += e;
  }
  v = zp;
  #pragma unroll
  for (int o = 32; o > 0; o >>= 1) v += __shfl_down(v, o, 64);
  if (lane == 0) red[wid] = v;
  __syncthreads();
  if (t == 0) bc[1] = red[0] + red[1] + red[2] + red[3];
  __syncthreads();
  const float iZ = 1.0f / bc[1];
  for (int i = t; i < cnt; i += 256)
    w_all[seg * SEGL + 1024 + dlo + i] *= iZ;
  if (t == 0) Dv[seg] = D;
}

// ---------------------------------------------------------------------------
// K2: truncated "same" conv. 512 blocks x 256 threads; block bx handles
// outputs [seg*2048 + M0, +256), seg = bx>>3, M0 = (bx&7)*256.
// Stages only the live y span; window read directly (block-uniform scalar).
// out[m] = sum_d w[1024+d] * seg[m-1-d], d in [-D, min(D,1023)]
// ---------------------------------------------------------------------------
__global__ __launch_bounds__(256) void k_conv(
    const float* __restrict__ y, const float* __restrict__ w_all,
    const int* __restrict__ Dv, float* __restrict__ out)
{
  __shared__ float S[2560];   // seg coord = sbase + idx

  const int t = threadIdx.x;
  const int bx0 = (int)blockIdx.x;
  const int bx = ((bx0 & 7) << 6) | (bx0 >> 3);   // same XCD as producer
  const int seg = bx >> 3;
  const int M0 = (bx & 7) << 8;
  const int sbase = M0 - 1026;

  const int D = Dv[seg];
  const int dlo = -D;
  const int dhi = (D < 1023) ? D : 1023;

  // live span of S: [1025-dhi, 1281+D)
  const int ilo = 1025 - dhi;
  const int ihi = 1281 + D;
  for (int i = ilo + t; i < ihi; i += 256) {
    const int g = sbase + i;
    S[i] = (g >= 0 && g < SEGL) ? y[seg * SEGL + g] : 0.0f;
  }
  __syncthreads();

  const float* wrow = w_all + seg * SEGL + 1024;
  float a = 0.0f;
  for (int d = dlo; d <= dhi; ++d)
    a = fmaf(wrow[d], S[t + 1025 - d], a);   // wrow[d] block-uniform
  out[seg * SEGL + M0 + t] = a;
}

// ---------------------------------------------------------------------------
extern "C" void kernel_launch(void* const* d_in, const int* in_sizes, int n_in,
                              void* d_out, int out_size, void* d_ws, size_t ws_size,
                              hipStream_t stream) {
  const float* x  = (const float*)d_in[0];
  const float* W1 = (const float*)d_in[1];
  const float* b1 = (const float*)d_in[2];
  const float* W2 = (const float*)d_in[3];
  const float* b2 = (const float*)d_in[4];
  const float* W3 = (const float*)d_in[5];
  const float* b3 = (const float*)d_in[6];
  float* out = (float*)d_out;

  char* ws = (char*)d_ws;
  float* y     = (float*)(ws);
  float* w_all = (float*)(ws + 524288);
  int*   Dv    = (int*)  (ws + 1048576);

  hipLaunchKernelGGL(k_y, dim3(512), dim3(256), 0, stream,
                     x, W1, b1, W2, b2, W3, b3, y, w_all, Dv);
  hipLaunchKernelGGL(k_conv, dim3(512), dim3(256), 0, stream,
                     y, w_all, Dv, out);
}